// Round 1
// baseline (307.606 us; speedup 1.0000x reference)
//
#include <hip/hip_runtime.h>

// Linear attention (chunked cumulative state), B=4 H=8 N=4096 D=E=64 CHUNK=128.
// fp32 baseline: phase1 per-chunk sums -> phase2 chunk prefix scan -> phase3 per-chunk output.

#define CHUNKSZ 128
#define DD 64
#define EE 64
#define NC 32          // N / CHUNK
#define NBH 32         // B*H
#define NSEQ 4096
#define EPSV 1e-6f
#define OUT0 (NBH * NSEQ * EE)           // 8,388,608 floats: start of Z output
#define KV_ELEMS (NBH * NC * DD * EE)    // 4,194,304 floats (16 MB) in ws
// ws layout: [0, KV_ELEMS) = per-chunk kv sums / exclusive prefixes
//            [KV_ELEMS, +NBH*NC*DD) = per-chunk k sums / exclusive prefixes

__global__ __launch_bounds__(256) void la_phase1(
    const float* __restrict__ k, const float* __restrict__ v,
    float* __restrict__ kv, float* __restrict__ ks)
{
    const int blk = blockIdx.x;           // bh*NC + c
    const int bh = blk / NC, c = blk % NC;
    const size_t rowbase = (size_t)bh * NSEQ + (size_t)c * CHUNKSZ;
    __shared__ float k_lds[CHUNKSZ][DD];
    __shared__ float v_lds[CHUNKSZ][DD];
    const int t = threadIdx.x;
    {
        const float4* kc = (const float4*)(k + rowbase * DD);
        const float4* vc = (const float4*)(v + rowbase * DD);
#pragma unroll
        for (int i = 0; i < (CHUNKSZ * DD / 4) / 256; ++i) {
            int idx = t + i * 256;
            ((float4*)k_lds)[idx] = kc[idx];
            ((float4*)v_lds)[idx] = vc[idx];
        }
    }
    __syncthreads();

    // per-chunk k column sums (threads 0..63)
    if (t < DD) {
        float s = 0.f;
        for (int m = 0; m < CHUNKSZ; ++m) s += k_lds[m][t];
        ks[((size_t)bh * NC + c) * DD + t] = s;
    }

    // per-chunk kv outer-product sums: thread -> d = t>>2, e in [(t&3)*16, +16)
    const int d = t >> 2;
    const int e0 = (t & 3) * 16;
    float4 acc[4] = {};
    for (int m = 0; m < CHUNKSZ; ++m) {
        float kd = k_lds[m][d];
        const float4* vrow = (const float4*)(&v_lds[m][e0]);
#pragma unroll
        for (int j = 0; j < 4; ++j) {
            float4 vv = vrow[j];
            acc[j].x += kd * vv.x; acc[j].y += kd * vv.y;
            acc[j].z += kd * vv.z; acc[j].w += kd * vv.w;
        }
    }
    float4* kvout = (float4*)(kv + (((size_t)bh * NC + c) * DD + d) * EE + e0);
#pragma unroll
    for (int j = 0; j < 4; ++j) kvout[j] = acc[j];
}

// Exclusive prefix scan over chunks, independent per (bh, d, e).
// grid = NBH*DD blocks of 64 threads (thread = e). Also writes final Z/S to out tail.
__global__ __launch_bounds__(64) void la_phase2(
    float* __restrict__ kv, float* __restrict__ ks, float* __restrict__ out)
{
    const int bid = blockIdx.x;           // bh*DD + d
    const int bh = bid / DD, d = bid % DD;
    const int e = threadIdx.x;
    float run = 0.f;
    for (int c = 0; c < NC; ++c) {
        size_t idx = (((size_t)bh * NC + c) * DD + d) * EE + e;
        float x = kv[idx];
        kv[idx] = run;
        run += x;
    }
    out[OUT0 + NBH * DD + ((size_t)bh * DD + d) * EE + e] = run;

    if (e == 0) {
        float rz = 0.f;
        for (int c = 0; c < NC; ++c) {
            size_t idx = ((size_t)bh * NC + c) * DD + d;
            float x = ks[idx];
            ks[idx] = rz;
            rz += x;
        }
        out[OUT0 + (size_t)bh * DD + d] = rz;
    }
}

// Per-chunk output: 256 threads = 128 rows x 2 e-halves (32 e each).
__global__ __launch_bounds__(256) void la_phase3(
    const float* __restrict__ q, const float* __restrict__ k,
    const float* __restrict__ v, const float* __restrict__ kv,
    const float* __restrict__ ks, float* __restrict__ out)
{
    const int blk = blockIdx.x;           // bh*NC + c
    const int bh = blk / NC, c = blk % NC;
    const size_t rowbase = (size_t)bh * NSEQ + (size_t)c * CHUNKSZ;
    __shared__ float k_lds[CHUNKSZ][DD];
    __shared__ float v_lds[CHUNKSZ][DD];
    const int t = threadIdx.x;
    {
        const float4* kc = (const float4*)(k + rowbase * DD);
        const float4* vc = (const float4*)(v + rowbase * DD);
#pragma unroll
        for (int i = 0; i < (CHUNKSZ * DD / 4) / 256; ++i) {
            int idx = t + i * 256;
            ((float4*)k_lds)[idx] = kc[idx];
            ((float4*)v_lds)[idx] = vc[idx];
        }
    }
    __syncthreads();

    const int r = t >> 1;
    const int e0 = (t & 1) * 32;

    // q row in registers (static indexing only)
    float4 qv[16];
    const float* qrowf = q + (rowbase + r) * DD;
    float qsum = 0.f;
    {
        const float4* qrow = (const float4*)qrowf;
#pragma unroll
        for (int i = 0; i < 16; ++i) {
            qv[i] = qrow[i];
            qsum += qv[i].x + qv[i].y + qv[i].z + qv[i].w;
        }
    }

    // q . Z_i
    const float* Zi = ks + ((size_t)bh * NC + c) * DD;
    float qdotZ = 0.f;
#pragma unroll
    for (int i = 0; i < 16; ++i) {
        float4 z = ((const float4*)Zi)[i];
        qdotZ += qv[i].x * z.x + qv[i].y * z.y + qv[i].z * z.z + qv[i].w * z.w;
    }

    // inter-chunk: acc[e] = sum_d q[d] * S_i[d][e]   (S_i broadcast across rows -> L1)
    float4 acc[8] = {};
    const float* Si = kv + (((size_t)bh * NC + c) * DD) * EE;
    for (int d = 0; d < DD; ++d) {
        float qd = qrowf[d];
        const float4* Srow = (const float4*)(Si + (size_t)d * EE + e0);
#pragma unroll
        for (int j = 0; j < 8; ++j) {
            float4 sv = Srow[j];
            acc[j].x += qd * sv.x; acc[j].y += qd * sv.y;
            acc[j].z += qd * sv.z; acc[j].w += qd * sv.w;
        }
    }

    // intra-chunk causal part
    float ssum = 0.f;
    for (int m = 0; m <= r; ++m) {
        const float4* krow = (const float4*)(&k_lds[m][0]);
        float s = 0.f;
#pragma unroll
        for (int i = 0; i < 16; ++i) {
            float4 kk = krow[i];
            s += qv[i].x * kk.x + qv[i].y * kk.y + qv[i].z * kk.z + qv[i].w * kk.w;
        }
        ssum += s;
        const float4* vrow = (const float4*)(&v_lds[m][e0]);
#pragma unroll
        for (int j = 0; j < 8; ++j) {
            float4 vv = vrow[j];
            acc[j].x += s * vv.x; acc[j].y += s * vv.y;
            acc[j].z += s * vv.z; acc[j].w += s * vv.w;
        }
    }

    const float dinv = 1.f / (qdotZ + ssum + EPSV * qsum);
    float4* orow = (float4*)(out + (rowbase + r) * EE + e0);
#pragma unroll
    for (int j = 0; j < 8; ++j) {
        float4 a = acc[j];
        a.x *= dinv; a.y *= dinv; a.z *= dinv; a.w *= dinv;
        orow[j] = a;
    }
}

extern "C" void kernel_launch(void* const* d_in, const int* in_sizes, int n_in,
                              void* d_out, int out_size, void* d_ws, size_t ws_size,
                              hipStream_t stream)
{
    (void)in_sizes; (void)n_in; (void)out_size; (void)ws_size;
    const float* q = (const float*)d_in[0];
    const float* k = (const float*)d_in[1];
    const float* v = (const float*)d_in[2];
    float* out = (float*)d_out;
    float* kv = (float*)d_ws;                 // 16 MB
    float* ks = kv + KV_ELEMS;                // +256 KB

    la_phase1<<<NBH * NC, 256, 0, stream>>>(k, v, kv, ks);
    la_phase2<<<NBH * DD, 64, 0, stream>>>(kv, ks, out);
    la_phase3<<<NBH * NC, 256, 0, stream>>>(q, k, v, kv, ks, out);
}

// Round 2
// 71.830 us; speedup vs baseline: 4.2824x; 4.2824x over previous
//
#include <hip/hip_runtime.h>

// Linear attention (chunked cumulative state), B=4 H=8 N=4096 D=E=64 CHUNK=128.
// phase1: per-chunk sums (fp32). phase2: chunk prefix scan (fp32).
// phase3: per-chunk output via bf16 MFMA (16x16x32), fp32 accumulate.

#define CHUNKSZ 128
#define DD 64
#define EE 64
#define NC 32          // N / CHUNK
#define NBH 32         // B*H
#define NSEQ 4096
#define EPSV 1e-6f
#define OUT0 (NBH * NSEQ * EE)           // start of Z output
#define KV_ELEMS (NBH * NC * DD * EE)

typedef short bf16x8 __attribute__((ext_vector_type(8)));
typedef short bf16x4 __attribute__((ext_vector_type(4)));
typedef float f32x4  __attribute__((ext_vector_type(4)));

__device__ __forceinline__ unsigned short f2bf(float f) {
    union { float f; unsigned u; } x; x.f = f;
    unsigned u = x.u + 0x7FFFu + ((x.u >> 16) & 1u);   // RNE
    return (unsigned short)(u >> 16);
}
__device__ __forceinline__ float bf2f(unsigned short s) {
    union { unsigned u; float f; } x; x.u = ((unsigned)s) << 16;
    return x.f;
}

__global__ __launch_bounds__(256) void la_phase1(
    const float* __restrict__ k, const float* __restrict__ v,
    float* __restrict__ kv, float* __restrict__ ks)
{
    const int blk = blockIdx.x;
    const int bh = blk / NC, c = blk % NC;
    const size_t rowbase = (size_t)bh * NSEQ + (size_t)c * CHUNKSZ;
    __shared__ float k_lds[CHUNKSZ][DD];
    __shared__ float v_lds[CHUNKSZ][DD];
    const int t = threadIdx.x;
    {
        const float4* kc = (const float4*)(k + rowbase * DD);
        const float4* vc = (const float4*)(v + rowbase * DD);
#pragma unroll
        for (int i = 0; i < (CHUNKSZ * DD / 4) / 256; ++i) {
            int idx = t + i * 256;
            ((float4*)k_lds)[idx] = kc[idx];
            ((float4*)v_lds)[idx] = vc[idx];
        }
    }
    __syncthreads();

    if (t < DD) {
        float s = 0.f;
        for (int m = 0; m < CHUNKSZ; ++m) s += k_lds[m][t];
        ks[((size_t)bh * NC + c) * DD + t] = s;
    }

    const int d = t >> 2;
    const int e0 = (t & 3) * 16;
    float4 acc[4] = {};
    for (int m = 0; m < CHUNKSZ; ++m) {
        float kd = k_lds[m][d];
        const float4* vrow = (const float4*)(&v_lds[m][e0]);
#pragma unroll
        for (int j = 0; j < 4; ++j) {
            float4 vv = vrow[j];
            acc[j].x += kd * vv.x; acc[j].y += kd * vv.y;
            acc[j].z += kd * vv.z; acc[j].w += kd * vv.w;
        }
    }
    float4* kvout = (float4*)(kv + (((size_t)bh * NC + c) * DD + d) * EE + e0);
#pragma unroll
    for (int j = 0; j < 4; ++j) kvout[j] = acc[j];
}

__global__ __launch_bounds__(64) void la_phase2(
    float* __restrict__ kv, float* __restrict__ ks, float* __restrict__ out)
{
    const int bid = blockIdx.x;
    const int bh = bid / DD, d = bid % DD;
    const int e = threadIdx.x;
    float run = 0.f;
    for (int c = 0; c < NC; ++c) {
        size_t idx = (((size_t)bh * NC + c) * DD + d) * EE + e;
        float x = kv[idx];
        kv[idx] = run;
        run += x;
    }
    out[OUT0 + NBH * DD + ((size_t)bh * DD + d) * EE + e] = run;

    if (e == 0) {
        float rz = 0.f;
        for (int c = 0; c < NC; ++c) {
            size_t idx = ((size_t)bh * NC + c) * DD + d;
            float x = ks[idx];
            ks[idx] = rz;
            rz += x;
        }
        out[OUT0 + (size_t)bh * DD + d] = rz;
    }
}

// Phase 3 with bf16 MFMA. 256 threads = 4 waves; wave w owns tile-rows ni in {w, w+4}.
// LDS layouts (all bf16/ushort):
//   k_lds : row-major [128][64], byte(m,d) = m*128 + ((d*2) ^ ((m&7)<<4))
//   s_lds : row-major [128 n][128 m], byte(n,m) = n*256 + ((m*2) ^ ((n&7)<<4))
//   st_lds: state^T [64 e][64 d], byte(e,d) = e*128 + ((d*2) ^ ((e&7)<<4))
//   v_lds : [m/8][e][m&7], byte(m,e) = (m>>3)*1024 + e*16 + (m&7)*2
__global__ __launch_bounds__(256) void la_phase3(
    const float* __restrict__ q, const float* __restrict__ k,
    const float* __restrict__ v, const float* __restrict__ kv,
    const float* __restrict__ ks, float* __restrict__ out)
{
    const int blk = blockIdx.x;
    const int bh = blk / NC, c = blk % NC;
    const size_t rowbase = (size_t)bh * NSEQ + (size_t)c * CHUNKSZ;

    __shared__ alignas(16) unsigned short k_lds[CHUNKSZ * DD];
    __shared__ alignas(16) unsigned short v_lds[CHUNKSZ * EE];
    __shared__ alignas(16) unsigned short s_lds[CHUNKSZ * CHUNKSZ];
    __shared__ alignas(16) unsigned short st_lds[DD * EE];
    __shared__ float dinv_lds[CHUNKSZ];

    char* kb  = (char*)k_lds;
    char* vb  = (char*)v_lds;
    char* sb  = (char*)s_lds;
    char* stb = (char*)st_lds;

    const int t  = threadIdx.x;
    const int w  = t >> 6;
    const int l  = t & 63;
    const int lg = l >> 4;     // lane group 0..3
    const int lm = l & 15;     // lane within group

    // ---------------- staging ----------------
    // zero s_lds (32KB): 128B per thread
    {
        bf16x8 z = {0,0,0,0,0,0,0,0};
#pragma unroll
        for (int i = 0; i < 8; ++i)
            *(bf16x8*)(sb + t * 128 + i * 16) = z;
    }
    // K -> k_lds (swizzled row-major)
    {
        const float4* kg = (const float4*)(k + rowbase * DD);
#pragma unroll
        for (int i = 0; i < 8; ++i) {
            int idx = t + i * 256;
            int m = idx >> 4, c4 = idx & 15;
            float4 f = kg[idx];
            bf16x4 u;
            u[0] = (short)f2bf(f.x); u[1] = (short)f2bf(f.y);
            u[2] = (short)f2bf(f.z); u[3] = (short)f2bf(f.w);
            int byt = m * 128 + ((c4 * 8) ^ ((m & 7) << 4));
            *(bf16x4*)(kb + byt) = u;
        }
    }
    // V -> v_lds ([m/8][e][m&7] subtile layout)
    {
        const float4* vg = (const float4*)(v + rowbase * EE);
#pragma unroll
        for (int i = 0; i < 8; ++i) {
            int idx = t + i * 256;
            int m = idx >> 4, e0 = (idx & 15) * 4;
            float4 f = vg[idx];
            int base = (m >> 3) * 1024 + (m & 7) * 2;
            *(unsigned short*)(vb + base + (e0 + 0) * 16) = f2bf(f.x);
            *(unsigned short*)(vb + base + (e0 + 1) * 16) = f2bf(f.y);
            *(unsigned short*)(vb + base + (e0 + 2) * 16) = f2bf(f.z);
            *(unsigned short*)(vb + base + (e0 + 3) * 16) = f2bf(f.w);
        }
    }
    // S_state -> st_lds (transposed [e][d], swizzled)
    {
        const float4* sg = (const float4*)(kv + ((size_t)(bh * NC + c) * DD) * EE);
#pragma unroll
        for (int i = 0; i < 4; ++i) {
            int idx = t + i * 256;
            int d = idx >> 4, e0 = (idx & 15) * 4;
            float4 f = sg[idx];
            float ff[4] = {f.x, f.y, f.z, f.w};
#pragma unroll
            for (int j = 0; j < 4; ++j) {
                int e = e0 + j;
                int byt = e * 128 + ((d * 2) ^ ((e & 7) << 4));
                *(unsigned short*)(stb + byt) = f2bf(ff[j]);
            }
        }
    }
    // Q A-fragments: a_q[ni2][kk], row n = 16*ni + lm, k d = 8*lg + 32*kk + i
    bf16x8 a_q[2][2];
#pragma unroll
    for (int ni2 = 0; ni2 < 2; ++ni2) {
        int ni = w + 4 * ni2;
        const float* qrow = q + (rowbase + 16 * ni + lm) * DD;
#pragma unroll
        for (int kk = 0; kk < 2; ++kk) {
            const float4* p = (const float4*)(qrow + 8 * lg + 32 * kk);
            float4 f0 = p[0], f1 = p[1];
            bf16x8 u;
            u[0] = (short)f2bf(f0.x); u[1] = (short)f2bf(f0.y);
            u[2] = (short)f2bf(f0.z); u[3] = (short)f2bf(f0.w);
            u[4] = (short)f2bf(f1.x); u[5] = (short)f2bf(f1.y);
            u[6] = (short)f2bf(f1.z); u[7] = (short)f2bf(f1.w);
            a_q[ni2][kk] = u;
        }
    }
    __syncthreads();

    // ---------------- QK^T -> masked S (bf16) in LDS ----------------
#pragma unroll
    for (int ni2 = 0; ni2 < 2; ++ni2) {
        const int ni = w + 4 * ni2;
        for (int mi = 0; mi <= ni; ++mi) {
            f32x4 cc = {0.f, 0.f, 0.f, 0.f};
            const int m = 16 * mi + lm;
#pragma unroll
            for (int kk = 0; kk < 2; ++kk) {
                int byt = m * 128 + (((8 * lg + 32 * kk) * 2) ^ ((m & 7) << 4));
                bf16x8 bk = *(bf16x8*)(kb + byt);
                cc = __builtin_amdgcn_mfma_f32_16x16x32_bf16(a_q[ni2][kk], bk, cc, 0, 0, 0);
            }
            const int nbase = 16 * ni + 4 * lg;
#pragma unroll
            for (int r = 0; r < 4; ++r) {
                int n = nbase + r;
                float val = (m <= n) ? cc[r] : 0.f;   // causal mask
                int byt = n * 256 + ((m * 2) ^ ((n & 7) << 4));
                *(unsigned short*)(sb + byt) = f2bf(val);
            }
        }
    }
    __syncthreads();

    // ---------------- per-row denominator (2 lanes per row) ----------------
    {
        const int n = t >> 1, h = t & 1;
        float ssum = 0.f;
#pragma unroll
        for (int s8 = 0; s8 < 8; ++s8) {
            int byt = n * 256 + ((128 * h + 16 * s8) ^ ((n & 7) << 4));
            bf16x8 sv = *(bf16x8*)(sb + byt);
#pragma unroll
            for (int j = 0; j < 8; ++j) ssum += bf2f((unsigned short)sv[j]);
        }
        const float* qrow = q + (rowbase + n) * DD + 32 * h;
        const float* Zi = ks + (size_t)(bh * NC + c) * DD + 32 * h;
        float qdot = 0.f, qs = 0.f;
#pragma unroll
        for (int d = 0; d < 32; ++d) {
            float qf = qrow[d];
            qdot += qf * Zi[d];
            qs += qf;
        }
        float tot = ssum + qdot + EPSV * qs;
        tot += __shfl_xor(tot, 1);
        if (h == 0) dinv_lds[n] = 1.f / tot;
    }

    // ---------------- O = Q*S_state + S*V ----------------
    f32x4 acc[2][4];
#pragma unroll
    for (int ni2 = 0; ni2 < 2; ++ni2) {
        const int ni = w + 4 * ni2;
        const int kmax = (ni >> 1) + 1;     // # of 32-wide m steps (causal)
#pragma unroll
        for (int ei = 0; ei < 4; ++ei) {
            f32x4 cc = {0.f, 0.f, 0.f, 0.f};
            const int e = 16 * ei + lm;
#pragma unroll
            for (int kk = 0; kk < 2; ++kk) {   // inter: Q x S_state
                int byt = e * 128 + (((8 * lg + 32 * kk) * 2) ^ ((e & 7) << 4));
                bf16x8 bs = *(bf16x8*)(stb + byt);
                cc = __builtin_amdgcn_mfma_f32_16x16x32_bf16(a_q[ni2][kk], bs, cc, 0, 0, 0);
            }
            const int n = 16 * ni + lm;
            for (int kk = 0; kk < kmax; ++kk) {   // intra: S x V
                int bytA = n * 256 + (((8 * lg + 32 * kk) * 2) ^ ((n & 7) << 4));
                bf16x8 as = *(bf16x8*)(sb + bytA);
                int bytB = (lg + 4 * kk) * 1024 + e * 16;
                bf16x8 bv = *(bf16x8*)(vb + bytB);
                cc = __builtin_amdgcn_mfma_f32_16x16x32_bf16(as, bv, cc, 0, 0, 0);
            }
            acc[ni2][ei] = cc;
        }
    }
    __syncthreads();

    // ---------------- epilogue: scale by dinv, store ----------------
#pragma unroll
    for (int ni2 = 0; ni2 < 2; ++ni2) {
        const int nbase = 16 * (w + 4 * ni2) + 4 * lg;
#pragma unroll
        for (int ei = 0; ei < 4; ++ei) {
            const int e = 16 * ei + lm;
#pragma unroll
            for (int r = 0; r < 4; ++r) {
                int n = nbase + r;
                out[(rowbase + n) * EE + e] = acc[ni2][ei][r] * dinv_lds[n];
            }
        }
    }
}

extern "C" void kernel_launch(void* const* d_in, const int* in_sizes, int n_in,
                              void* d_out, int out_size, void* d_ws, size_t ws_size,
                              hipStream_t stream)
{
    (void)in_sizes; (void)n_in; (void)out_size; (void)ws_size;
    const float* q = (const float*)d_in[0];
    const float* k = (const float*)d_in[1];
    const float* v = (const float*)d_in[2];
    float* out = (float*)d_out;
    float* kv = (float*)d_ws;                 // 16 MB
    float* ks = kv + KV_ELEMS;                // +256 KB

    la_phase1<<<NBH * NC, 256, 0, stream>>>(k, v, kv, ks);
    la_phase2<<<NBH * DD, 64, 0, stream>>>(kv, ks, out);
    la_phase3<<<NBH * NC, 256, 0, stream>>>(q, k, v, kv, ks, out);
}

// Round 3
// 58.523 us; speedup vs baseline: 5.2561x; 1.2274x over previous
//
#include <hip/hip_runtime.h>

// Linear attention (chunked cumulative state), B=4 H=8 N=4096 D=E=64 CHUNK=128.
// phase1: per-chunk K^T V via bf16 MFMA + fp32 k-colsums. phase2: register prefix scan.
// phase3: per-chunk output via bf16 MFMA (16x16x32), fp32 accumulate.

#define CHUNKSZ 128
#define DD 64
#define EE 64
#define NC 32          // N / CHUNK
#define NBH 32         // B*H
#define NSEQ 4096
#define EPSV 1e-6f
#define OUT0 (NBH * NSEQ * EE)           // start of Z output
#define KV_ELEMS (NBH * NC * DD * EE)

typedef short bf16x8 __attribute__((ext_vector_type(8)));
typedef short bf16x4 __attribute__((ext_vector_type(4)));
typedef float f32x4  __attribute__((ext_vector_type(4)));

__device__ __forceinline__ unsigned short f2bf(float f) {
    union { float f; unsigned u; } x; x.f = f;
    unsigned u = x.u + 0x7FFFu + ((x.u >> 16) & 1u);   // RNE
    return (unsigned short)(u >> 16);
}
__device__ __forceinline__ float bf2f(unsigned short s) {
    union { unsigned u; float f; } x; x.u = ((unsigned)s) << 16;
    return x.f;
}

// ---------------- phase 1: kv[d][e] = sum_m K[m][d] V[m][e] via MFMA ----------------
// LDS layouts: kT/vT subtiled [m/8][col][m&7] bf16 so A/B fragments are contiguous b128.
__global__ __launch_bounds__(256) void la_phase1(
    const float* __restrict__ k, const float* __restrict__ v,
    float* __restrict__ kv, float* __restrict__ ks)
{
    const int blk = blockIdx.x;
    const int bh = blk / NC, c = blk % NC;
    const size_t rowbase = (size_t)bh * NSEQ + (size_t)c * CHUNKSZ;

    __shared__ alignas(16) unsigned short kT[CHUNKSZ * DD];
    __shared__ alignas(16) unsigned short vT[CHUNKSZ * EE];
    __shared__ float ksp[4][DD];

    char* kb = (char*)kT;
    char* vb = (char*)vT;

    const int t = threadIdx.x;
    const int w = t >> 6, l = t & 63;
    const int lg = l >> 4, lm = l & 15;

    // staging + fp32 k column partial sums
    float kpart[4] = {0.f, 0.f, 0.f, 0.f};
    {
        const float4* kg = (const float4*)(k + rowbase * DD);
        const float4* vg = (const float4*)(v + rowbase * EE);
        const int d0 = (t & 15) * 4;
#pragma unroll
        for (int i = 0; i < 8; ++i) {
            int idx = t + 256 * i;
            int m = idx >> 4;
            float4 f = kg[idx];
            kpart[0] += f.x; kpart[1] += f.y; kpart[2] += f.z; kpart[3] += f.w;
            int base = (m >> 3) * 1024 + (m & 7) * 2;
            *(unsigned short*)(kb + base + (d0 + 0) * 16) = f2bf(f.x);
            *(unsigned short*)(kb + base + (d0 + 1) * 16) = f2bf(f.y);
            *(unsigned short*)(kb + base + (d0 + 2) * 16) = f2bf(f.z);
            *(unsigned short*)(kb + base + (d0 + 3) * 16) = f2bf(f.w);
        }
#pragma unroll
        for (int i = 0; i < 8; ++i) {
            int idx = t + 256 * i;
            int m = idx >> 4;
            float4 f = vg[idx];
            int base = (m >> 3) * 1024 + (m & 7) * 2;
            *(unsigned short*)(vb + base + (d0 + 0) * 16) = f2bf(f.x);
            *(unsigned short*)(vb + base + (d0 + 1) * 16) = f2bf(f.y);
            *(unsigned short*)(vb + base + (d0 + 2) * 16) = f2bf(f.z);
            *(unsigned short*)(vb + base + (d0 + 3) * 16) = f2bf(f.w);
        }
    }
    // lanes l, l^16, l^32, l^48 share the same d0 (different m groups)
#pragma unroll
    for (int j = 0; j < 4; ++j) {
        kpart[j] += __shfl_xor(kpart[j], 16);
        kpart[j] += __shfl_xor(kpart[j], 32);
    }
    if (l < 16) {
#pragma unroll
        for (int j = 0; j < 4; ++j) ksp[w][l * 4 + j] = kpart[j];
    }
    __syncthreads();

    // MFMA: wave w owns d-tile w (rows 16w..16w+15), all 4 e-tiles, K=128 in 4 steps.
    f32x4 acc[4] = {};
#pragma unroll
    for (int kk = 0; kk < 4; ++kk) {
        bf16x8 aK = *(bf16x8*)(kb + (lg + 4 * kk) * 1024 + (16 * w + lm) * 16);
#pragma unroll
        for (int ei = 0; ei < 4; ++ei) {
            bf16x8 bV = *(bf16x8*)(vb + (lg + 4 * kk) * 1024 + (16 * ei + lm) * 16);
            acc[ei] = __builtin_amdgcn_mfma_f32_16x16x32_bf16(aK, bV, acc[ei], 0, 0, 0);
        }
    }
    float* kvout = kv + (size_t)(bh * NC + c) * DD * EE;
#pragma unroll
    for (int ei = 0; ei < 4; ++ei) {
#pragma unroll
        for (int r = 0; r < 4; ++r) {
            int d = 16 * w + 4 * lg + r;
            kvout[(size_t)d * EE + 16 * ei + lm] = acc[ei][r];
        }
    }
    if (t < DD)
        ks[(size_t)(bh * NC + c) * DD + t] = ksp[0][t] + ksp[1][t] + ksp[2][t] + ksp[3][t];
}

// ---------------- phase 2: exclusive prefix scan over chunks, in registers ----------------
// blocks 0..511 (64 thr): kv scan, thread owns one (bh,d,e4) float4 lane.
// blocks 512..543 (64 thr): ks scan, thread owns one (bh,d).
__global__ __launch_bounds__(64) void la_phase2(
    float* __restrict__ kv, float* __restrict__ ks, float* __restrict__ out)
{
    const int bid = blockIdx.x, t = threadIdx.x;
    if (bid < 512) {
        const int gid = bid * 64 + t;            // 0..32767
        const int bh = gid >> 10;
        const int rem = gid & 1023;              // d*16 + e4
        float* base = kv + (size_t)bh * (NC * DD * EE) + (size_t)rem * 4;
        float4 vals[32];
#pragma unroll
        for (int c = 0; c < 32; ++c)
            vals[c] = *(const float4*)(base + (size_t)c * (DD * EE));
        float4 run = {0.f, 0.f, 0.f, 0.f};
#pragma unroll
        for (int c = 0; c < 32; ++c) {
            float4 x = vals[c];
            *(float4*)(base + (size_t)c * (DD * EE)) = run;
            run.x += x.x; run.y += x.y; run.z += x.z; run.w += x.w;
        }
        *(float4*)(out + OUT0 + NBH * DD + (size_t)gid * 4) = run;   // S tail
    } else {
        const int tid = (bid - 512) * 64 + t;    // 0..2047 = bh*64 + d
        const int bh = tid >> 6, d = tid & 63;
        float vals[32];
#pragma unroll
        for (int c = 0; c < 32; ++c)
            vals[c] = ks[(size_t)(bh * NC + c) * DD + d];
        float run = 0.f;
#pragma unroll
        for (int c = 0; c < 32; ++c) {
            float x = vals[c];
            ks[(size_t)(bh * NC + c) * DD + d] = run;
            run += x;
        }
        out[OUT0 + tid] = run;                   // Z tail
    }
}

// ---------------- phase 3: per-chunk output via MFMA (unchanged from round 2) ----------------
__global__ __launch_bounds__(256) void la_phase3(
    const float* __restrict__ q, const float* __restrict__ k,
    const float* __restrict__ v, const float* __restrict__ kv,
    const float* __restrict__ ks, float* __restrict__ out)
{
    const int blk = blockIdx.x;
    const int bh = blk / NC, c = blk % NC;
    const size_t rowbase = (size_t)bh * NSEQ + (size_t)c * CHUNKSZ;

    __shared__ alignas(16) unsigned short k_lds[CHUNKSZ * DD];
    __shared__ alignas(16) unsigned short v_lds[CHUNKSZ * EE];
    __shared__ alignas(16) unsigned short s_lds[CHUNKSZ * CHUNKSZ];
    __shared__ alignas(16) unsigned short st_lds[DD * EE];
    __shared__ float dinv_lds[CHUNKSZ];

    char* kb  = (char*)k_lds;
    char* vb  = (char*)v_lds;
    char* sb  = (char*)s_lds;
    char* stb = (char*)st_lds;

    const int t  = threadIdx.x;
    const int w  = t >> 6;
    const int l  = t & 63;
    const int lg = l >> 4;
    const int lm = l & 15;

    {
        bf16x8 z = {0,0,0,0,0,0,0,0};
#pragma unroll
        for (int i = 0; i < 8; ++i)
            *(bf16x8*)(sb + t * 128 + i * 16) = z;
    }
    {
        const float4* kg = (const float4*)(k + rowbase * DD);
#pragma unroll
        for (int i = 0; i < 8; ++i) {
            int idx = t + i * 256;
            int m = idx >> 4, c4 = idx & 15;
            float4 f = kg[idx];
            bf16x4 u;
            u[0] = (short)f2bf(f.x); u[1] = (short)f2bf(f.y);
            u[2] = (short)f2bf(f.z); u[3] = (short)f2bf(f.w);
            int byt = m * 128 + ((c4 * 8) ^ ((m & 7) << 4));
            *(bf16x4*)(kb + byt) = u;
        }
    }
    {
        const float4* vg = (const float4*)(v + rowbase * EE);
#pragma unroll
        for (int i = 0; i < 8; ++i) {
            int idx = t + i * 256;
            int m = idx >> 4, e0 = (idx & 15) * 4;
            float4 f = vg[idx];
            int base = (m >> 3) * 1024 + (m & 7) * 2;
            *(unsigned short*)(vb + base + (e0 + 0) * 16) = f2bf(f.x);
            *(unsigned short*)(vb + base + (e0 + 1) * 16) = f2bf(f.y);
            *(unsigned short*)(vb + base + (e0 + 2) * 16) = f2bf(f.z);
            *(unsigned short*)(vb + base + (e0 + 3) * 16) = f2bf(f.w);
        }
    }
    {
        const float4* sg = (const float4*)(kv + ((size_t)(bh * NC + c) * DD) * EE);
#pragma unroll
        for (int i = 0; i < 4; ++i) {
            int idx = t + i * 256;
            int d = idx >> 4, e0 = (idx & 15) * 4;
            float4 f = sg[idx];
            float ff[4] = {f.x, f.y, f.z, f.w};
#pragma unroll
            for (int j = 0; j < 4; ++j) {
                int e = e0 + j;
                int byt = e * 128 + ((d * 2) ^ ((e & 7) << 4));
                *(unsigned short*)(stb + byt) = f2bf(ff[j]);
            }
        }
    }
    bf16x8 a_q[2][2];
#pragma unroll
    for (int ni2 = 0; ni2 < 2; ++ni2) {
        int ni = w + 4 * ni2;
        const float* qrow = q + (rowbase + 16 * ni + lm) * DD;
#pragma unroll
        for (int kk = 0; kk < 2; ++kk) {
            const float4* p = (const float4*)(qrow + 8 * lg + 32 * kk);
            float4 f0 = p[0], f1 = p[1];
            bf16x8 u;
            u[0] = (short)f2bf(f0.x); u[1] = (short)f2bf(f0.y);
            u[2] = (short)f2bf(f0.z); u[3] = (short)f2bf(f0.w);
            u[4] = (short)f2bf(f1.x); u[5] = (short)f2bf(f1.y);
            u[6] = (short)f2bf(f1.z); u[7] = (short)f2bf(f1.w);
            a_q[ni2][kk] = u;
        }
    }
    __syncthreads();

#pragma unroll
    for (int ni2 = 0; ni2 < 2; ++ni2) {
        const int ni = w + 4 * ni2;
        for (int mi = 0; mi <= ni; ++mi) {
            f32x4 cc = {0.f, 0.f, 0.f, 0.f};
            const int m = 16 * mi + lm;
#pragma unroll
            for (int kk = 0; kk < 2; ++kk) {
                int byt = m * 128 + (((8 * lg + 32 * kk) * 2) ^ ((m & 7) << 4));
                bf16x8 bk = *(bf16x8*)(kb + byt);
                cc = __builtin_amdgcn_mfma_f32_16x16x32_bf16(a_q[ni2][kk], bk, cc, 0, 0, 0);
            }
            const int nbase = 16 * ni + 4 * lg;
#pragma unroll
            for (int r = 0; r < 4; ++r) {
                int n = nbase + r;
                float val = (m <= n) ? cc[r] : 0.f;
                int byt = n * 256 + ((m * 2) ^ ((n & 7) << 4));
                *(unsigned short*)(sb + byt) = f2bf(val);
            }
        }
    }
    __syncthreads();

    {
        const int n = t >> 1, h = t & 1;
        float ssum = 0.f;
#pragma unroll
        for (int s8 = 0; s8 < 8; ++s8) {
            int byt = n * 256 + ((128 * h + 16 * s8) ^ ((n & 7) << 4));
            bf16x8 sv = *(bf16x8*)(sb + byt);
#pragma unroll
            for (int j = 0; j < 8; ++j) ssum += bf2f((unsigned short)sv[j]);
        }
        const float* qrow = q + (rowbase + n) * DD + 32 * h;
        const float* Zi = ks + (size_t)(bh * NC + c) * DD + 32 * h;
        float qdot = 0.f, qs = 0.f;
#pragma unroll
        for (int d = 0; d < 32; ++d) {
            float qf = qrow[d];
            qdot += qf * Zi[d];
            qs += qf;
        }
        float tot = ssum + qdot + EPSV * qs;
        tot += __shfl_xor(tot, 1);
        if (h == 0) dinv_lds[n] = 1.f / tot;
    }

    f32x4 acc[2][4];
#pragma unroll
    for (int ni2 = 0; ni2 < 2; ++ni2) {
        const int ni = w + 4 * ni2;
        const int kmax = (ni >> 1) + 1;
#pragma unroll
        for (int ei = 0; ei < 4; ++ei) {
            f32x4 cc = {0.f, 0.f, 0.f, 0.f};
            const int e = 16 * ei + lm;
#pragma unroll
            for (int kk = 0; kk < 2; ++kk) {
                int byt = e * 128 + (((8 * lg + 32 * kk) * 2) ^ ((e & 7) << 4));
                bf16x8 bs = *(bf16x8*)(stb + byt);
                cc = __builtin_amdgcn_mfma_f32_16x16x32_bf16(a_q[ni2][kk], bs, cc, 0, 0, 0);
            }
            const int n = 16 * ni + lm;
            for (int kk = 0; kk < kmax; ++kk) {
                int bytA = n * 256 + (((8 * lg + 32 * kk) * 2) ^ ((n & 7) << 4));
                bf16x8 as = *(bf16x8*)(sb + bytA);
                int bytB = (lg + 4 * kk) * 1024 + e * 16;
                bf16x8 bv = *(bf16x8*)(vb + bytB);
                cc = __builtin_amdgcn_mfma_f32_16x16x32_bf16(as, bv, cc, 0, 0, 0);
            }
            acc[ni2][ei] = cc;
        }
    }
    __syncthreads();

#pragma unroll
    for (int ni2 = 0; ni2 < 2; ++ni2) {
        const int nbase = 16 * (w + 4 * ni2) + 4 * lg;
#pragma unroll
        for (int ei = 0; ei < 4; ++ei) {
            const int e = 16 * ei + lm;
#pragma unroll
            for (int r = 0; r < 4; ++r) {
                int n = nbase + r;
                out[(rowbase + n) * EE + e] = acc[ni2][ei][r] * dinv_lds[n];
            }
        }
    }
}

extern "C" void kernel_launch(void* const* d_in, const int* in_sizes, int n_in,
                              void* d_out, int out_size, void* d_ws, size_t ws_size,
                              hipStream_t stream)
{
    (void)in_sizes; (void)n_in; (void)out_size; (void)ws_size;
    const float* q = (const float*)d_in[0];
    const float* k = (const float*)d_in[1];
    const float* v = (const float*)d_in[2];
    float* out = (float*)d_out;
    float* kv = (float*)d_ws;                 // 16 MB
    float* ks = kv + KV_ELEMS;                // +256 KB

    la_phase1<<<NBH * NC, 256, 0, stream>>>(k, v, kv, ks);
    la_phase2<<<544, 64, 0, stream>>>(kv, ks, out);
    la_phase3<<<NBH * NC, 256, 0, stream>>>(q, k, v, kv, ks, out);
}

// Round 4
// 54.979 us; speedup vs baseline: 5.5950x; 1.0645x over previous
//
#include <hip/hip_runtime.h>

// Linear attention (chunked cumulative state), B=4 H=8 N=4096 D=E=64 CHUNK=128.
// phase1: per-chunk K^T V via bf16 MFMA (states stored bf16, transposed [e][d]) + fp32 k-colsums.
// phase2: register prefix scan over chunks (fp32 accum, bf16 prefixes, fp32 tails).
// phase3: per-chunk output via bf16 MFMA (16x16x32), fp32 accumulate.

#define CHUNKSZ 128
#define DD 64
#define EE 64
#define NC 32          // N / CHUNK
#define NBH 32         // B*H
#define NSEQ 4096
#define EPSV 1e-6f
#define OUT0 (NBH * NSEQ * EE)           // start of Z output
#define KV_ELEMS (NBH * NC * DD * EE)    // ushort count

typedef short bf16x8 __attribute__((ext_vector_type(8)));
typedef short bf16x4 __attribute__((ext_vector_type(4)));
typedef float f32x4  __attribute__((ext_vector_type(4)));

__device__ __forceinline__ unsigned short f2bf(float f) {
    union { float f; unsigned u; } x; x.f = f;
    unsigned u = x.u + 0x7FFFu + ((x.u >> 16) & 1u);   // RNE
    return (unsigned short)(u >> 16);
}
__device__ __forceinline__ float bf2f(unsigned short s) {
    union { unsigned u; float f; } x; x.u = ((unsigned)s) << 16;
    return x.f;
}

// ---------------- phase 1: kvT[e][d] = sum_m K[m][d] V[m][e]  (bf16) ----------------
__global__ __launch_bounds__(256) void la_phase1(
    const float* __restrict__ k, const float* __restrict__ v,
    unsigned short* __restrict__ kvT, float* __restrict__ ks)
{
    const int blk = blockIdx.x;
    const int bh = blk / NC, c = blk % NC;
    const size_t rowbase = (size_t)bh * NSEQ + (size_t)c * CHUNKSZ;

    __shared__ alignas(16) unsigned short kT[CHUNKSZ * DD];
    __shared__ alignas(16) unsigned short vT[CHUNKSZ * EE];
    __shared__ float ksp[4][DD];

    char* kb = (char*)kT;
    char* vb = (char*)vT;

    const int t = threadIdx.x;
    const int w = t >> 6, l = t & 63;
    const int lg = l >> 4, lm = l & 15;

    float kpart[4] = {0.f, 0.f, 0.f, 0.f};
    {
        const float4* kg = (const float4*)(k + rowbase * DD);
        const float4* vg = (const float4*)(v + rowbase * EE);
        const int d0 = (t & 15) * 4;
#pragma unroll
        for (int i = 0; i < 8; ++i) {
            int idx = t + 256 * i;
            int m = idx >> 4;
            float4 f = kg[idx];
            kpart[0] += f.x; kpart[1] += f.y; kpart[2] += f.z; kpart[3] += f.w;
            int base = (m >> 3) * 1024 + (m & 7) * 2;
            *(unsigned short*)(kb + base + (d0 + 0) * 16) = f2bf(f.x);
            *(unsigned short*)(kb + base + (d0 + 1) * 16) = f2bf(f.y);
            *(unsigned short*)(kb + base + (d0 + 2) * 16) = f2bf(f.z);
            *(unsigned short*)(kb + base + (d0 + 3) * 16) = f2bf(f.w);
        }
#pragma unroll
        for (int i = 0; i < 8; ++i) {
            int idx = t + 256 * i;
            int m = idx >> 4;
            float4 f = vg[idx];
            int base = (m >> 3) * 1024 + (m & 7) * 2;
            *(unsigned short*)(vb + base + (d0 + 0) * 16) = f2bf(f.x);
            *(unsigned short*)(vb + base + (d0 + 1) * 16) = f2bf(f.y);
            *(unsigned short*)(vb + base + (d0 + 2) * 16) = f2bf(f.z);
            *(unsigned short*)(vb + base + (d0 + 3) * 16) = f2bf(f.w);
        }
    }
#pragma unroll
    for (int j = 0; j < 4; ++j) {
        kpart[j] += __shfl_xor(kpart[j], 16);
        kpart[j] += __shfl_xor(kpart[j], 32);
    }
    if (l < 16) {
#pragma unroll
        for (int j = 0; j < 4; ++j) ksp[w][l * 4 + j] = kpart[j];
    }
    __syncthreads();

    f32x4 acc[4] = {};
#pragma unroll
    for (int kk = 0; kk < 4; ++kk) {
        bf16x8 aK = *(bf16x8*)(kb + (lg + 4 * kk) * 1024 + (16 * w + lm) * 16);
#pragma unroll
        for (int ei = 0; ei < 4; ++ei) {
            bf16x8 bV = *(bf16x8*)(vb + (lg + 4 * kk) * 1024 + (16 * ei + lm) * 16);
            acc[ei] = __builtin_amdgcn_mfma_f32_16x16x32_bf16(aK, bV, acc[ei], 0, 0, 0);
        }
    }
    // C-frag: row d = 16w+4lg+r, col e = 16ei+lm -> store transposed [e][d] bf16
    unsigned short* kvout = kvT + (size_t)(bh * NC + c) * DD * EE;
#pragma unroll
    for (int ei = 0; ei < 4; ++ei) {
        bf16x4 u;
        u[0] = (short)f2bf(acc[ei][0]); u[1] = (short)f2bf(acc[ei][1]);
        u[2] = (short)f2bf(acc[ei][2]); u[3] = (short)f2bf(acc[ei][3]);
        *(bf16x4*)(kvout + (16 * ei + lm) * DD + 16 * w + 4 * lg) = u;
    }
    if (t < DD)
        ks[(size_t)(bh * NC + c) * DD + t] = ksp[0][t] + ksp[1][t] + ksp[2][t] + ksp[3][t];
}

// ---------------- phase 2: exclusive prefix scan over chunks ----------------
// blocks 0..255 (64 thr): kvT scan, thread owns 8 consecutive [e][d] elements.
// blocks 256..287 (64 thr): ks scan (fp32), thread owns one (bh,d).
__global__ __launch_bounds__(64) void la_phase2(
    unsigned short* __restrict__ kvT, float* __restrict__ ks, float* __restrict__ out)
{
    const int bid = blockIdx.x, t = threadIdx.x;
    if (bid < 256) {
        const int gid = bid * 64 + t;            // 0..16383
        const int bh = gid >> 9;
        const int g = gid & 511;                 // group of 8 ushorts in [e][d] tile
        unsigned short* base = kvT + (size_t)bh * (NC * DD * EE) + (size_t)g * 8;
        bf16x8 vals[NC];
#pragma unroll
        for (int c = 0; c < NC; ++c)
            vals[c] = *(const bf16x8*)(base + (size_t)c * (DD * EE));
        float run[8] = {};
#pragma unroll
        for (int c = 0; c < NC; ++c) {
            bf16x8 pr;
#pragma unroll
            for (int j = 0; j < 8; ++j) pr[j] = (short)f2bf(run[j]);
            *(bf16x8*)(base + (size_t)c * (DD * EE)) = pr;
#pragma unroll
            for (int j = 0; j < 8; ++j) run[j] += bf2f((unsigned short)vals[c][j]);
        }
        // S tail (fp32, [d][e] layout): g = e*8 + d0/8
        const int e = g >> 3, d0 = (g & 7) * 8;
        float* Sout = out + OUT0 + NBH * DD + (size_t)bh * DD * EE;
#pragma unroll
        for (int j = 0; j < 8; ++j)
            Sout[(size_t)(d0 + j) * EE + e] = run[j];
    } else {
        const int tid = (bid - 256) * 64 + t;    // 0..2047 = bh*64 + d
        const int bh = tid >> 6, d = tid & 63;
        float vals[NC];
#pragma unroll
        for (int c = 0; c < NC; ++c)
            vals[c] = ks[(size_t)(bh * NC + c) * DD + d];
        float run = 0.f;
#pragma unroll
        for (int c = 0; c < NC; ++c) {
            float x = vals[c];
            ks[(size_t)(bh * NC + c) * DD + d] = run;
            run += x;
        }
        out[OUT0 + tid] = run;                   // Z tail
    }
}

// ---------------- phase 3: per-chunk output via MFMA ----------------
__global__ __launch_bounds__(256) void la_phase3(
    const float* __restrict__ q, const float* __restrict__ k,
    const float* __restrict__ v, const unsigned short* __restrict__ kvT,
    const float* __restrict__ ks, float* __restrict__ out)
{
    const int blk = blockIdx.x;
    const int bh = blk / NC, c = blk % NC;
    const size_t rowbase = (size_t)bh * NSEQ + (size_t)c * CHUNKSZ;

    __shared__ alignas(16) unsigned short k_lds[CHUNKSZ * DD];
    __shared__ alignas(16) unsigned short v_lds[CHUNKSZ * EE];
    __shared__ alignas(16) unsigned short s_lds[CHUNKSZ * CHUNKSZ];
    __shared__ alignas(16) unsigned short st_lds[DD * EE];
    __shared__ float dinv_lds[CHUNKSZ];

    char* kb  = (char*)k_lds;
    char* vb  = (char*)v_lds;
    char* sb  = (char*)s_lds;
    char* stb = (char*)st_lds;

    const int t  = threadIdx.x;
    const int w  = t >> 6;
    const int l  = t & 63;
    const int lg = l >> 4;
    const int lm = l & 15;

    {
        bf16x8 z = {0,0,0,0,0,0,0,0};
#pragma unroll
        for (int i = 0; i < 8; ++i)
            *(bf16x8*)(sb + t * 128 + i * 16) = z;
    }
    {
        const float4* kg = (const float4*)(k + rowbase * DD);
#pragma unroll
        for (int i = 0; i < 8; ++i) {
            int idx = t + i * 256;
            int m = idx >> 4, c4 = idx & 15;
            float4 f = kg[idx];
            bf16x4 u;
            u[0] = (short)f2bf(f.x); u[1] = (short)f2bf(f.y);
            u[2] = (short)f2bf(f.z); u[3] = (short)f2bf(f.w);
            int byt = m * 128 + ((c4 * 8) ^ ((m & 7) << 4));
            *(bf16x4*)(kb + byt) = u;
        }
    }
    {
        const float4* vg = (const float4*)(v + rowbase * EE);
#pragma unroll
        for (int i = 0; i < 8; ++i) {
            int idx = t + i * 256;
            int m = idx >> 4, e0 = (idx & 15) * 4;
            float4 f = vg[idx];
            int base = (m >> 3) * 1024 + (m & 7) * 2;
            *(unsigned short*)(vb + base + (e0 + 0) * 16) = f2bf(f.x);
            *(unsigned short*)(vb + base + (e0 + 1) * 16) = f2bf(f.y);
            *(unsigned short*)(vb + base + (e0 + 2) * 16) = f2bf(f.z);
            *(unsigned short*)(vb + base + (e0 + 3) * 16) = f2bf(f.w);
        }
    }
    {
        // state tile already bf16 [e][d]: pure copy into swizzled st_lds
        const unsigned short* sg = kvT + (size_t)(bh * NC + c) * DD * EE;
#pragma unroll
        for (int i = 0; i < 2; ++i) {
            int idx = t + 256 * i;              // 0..511
            int e = idx >> 3;
            bf16x8 x = *(const bf16x8*)(sg + (size_t)idx * 8);
            int byt = e * 128 + (((idx & 7) * 16) ^ ((e & 7) << 4));
            *(bf16x8*)(stb + byt) = x;
        }
    }
    bf16x8 a_q[2][2];
#pragma unroll
    for (int ni2 = 0; ni2 < 2; ++ni2) {
        int ni = w + 4 * ni2;
        const float* qrow = q + (rowbase + 16 * ni + lm) * DD;
#pragma unroll
        for (int kk = 0; kk < 2; ++kk) {
            const float4* p = (const float4*)(qrow + 8 * lg + 32 * kk);
            float4 f0 = p[0], f1 = p[1];
            bf16x8 u;
            u[0] = (short)f2bf(f0.x); u[1] = (short)f2bf(f0.y);
            u[2] = (short)f2bf(f0.z); u[3] = (short)f2bf(f0.w);
            u[4] = (short)f2bf(f1.x); u[5] = (short)f2bf(f1.y);
            u[6] = (short)f2bf(f1.z); u[7] = (short)f2bf(f1.w);
            a_q[ni2][kk] = u;
        }
    }
    __syncthreads();

#pragma unroll
    for (int ni2 = 0; ni2 < 2; ++ni2) {
        const int ni = w + 4 * ni2;
        for (int mi = 0; mi <= ni; ++mi) {
            f32x4 cc = {0.f, 0.f, 0.f, 0.f};
            const int m = 16 * mi + lm;
#pragma unroll
            for (int kk = 0; kk < 2; ++kk) {
                int byt = m * 128 + (((8 * lg + 32 * kk) * 2) ^ ((m & 7) << 4));
                bf16x8 bk = *(bf16x8*)(kb + byt);
                cc = __builtin_amdgcn_mfma_f32_16x16x32_bf16(a_q[ni2][kk], bk, cc, 0, 0, 0);
            }
            const int nbase = 16 * ni + 4 * lg;
#pragma unroll
            for (int r = 0; r < 4; ++r) {
                int n = nbase + r;
                float val = (m <= n) ? cc[r] : 0.f;
                int byt = n * 256 + ((m * 2) ^ ((n & 7) << 4));
                *(unsigned short*)(sb + byt) = f2bf(val);
            }
        }
    }
    __syncthreads();

    {
        const int n = t >> 1, h = t & 1;
        float ssum = 0.f;
#pragma unroll
        for (int s8 = 0; s8 < 8; ++s8) {
            int byt = n * 256 + ((128 * h + 16 * s8) ^ ((n & 7) << 4));
            bf16x8 sv = *(bf16x8*)(sb + byt);
#pragma unroll
            for (int j = 0; j < 8; ++j) ssum += bf2f((unsigned short)sv[j]);
        }
        const float* qrow = q + (rowbase + n) * DD + 32 * h;
        const float* Zi = ks + (size_t)(bh * NC + c) * DD + 32 * h;
        float qdot = 0.f, qs = 0.f;
#pragma unroll
        for (int d = 0; d < 32; ++d) {
            float qf = qrow[d];
            qdot += qf * Zi[d];
            qs += qf;
        }
        float tot = ssum + qdot + EPSV * qs;
        tot += __shfl_xor(tot, 1);
        if (h == 0) dinv_lds[n] = 1.f / tot;
    }

    f32x4 acc[2][4];
#pragma unroll
    for (int ni2 = 0; ni2 < 2; ++ni2) {
        const int ni = w + 4 * ni2;
        const int kmax = (ni >> 1) + 1;
#pragma unroll
        for (int ei = 0; ei < 4; ++ei) {
            f32x4 cc = {0.f, 0.f, 0.f, 0.f};
            const int e = 16 * ei + lm;
#pragma unroll
            for (int kk = 0; kk < 2; ++kk) {
                int byt = e * 128 + (((8 * lg + 32 * kk) * 2) ^ ((e & 7) << 4));
                bf16x8 bs = *(bf16x8*)(stb + byt);
                cc = __builtin_amdgcn_mfma_f32_16x16x32_bf16(a_q[ni2][kk], bs, cc, 0, 0, 0);
            }
            const int n = 16 * ni + lm;
            for (int kk = 0; kk < kmax; ++kk) {
                int bytA = n * 256 + (((8 * lg + 32 * kk) * 2) ^ ((n & 7) << 4));
                bf16x8 as = *(bf16x8*)(sb + bytA);
                int bytB = (lg + 4 * kk) * 1024 + e * 16;
                bf16x8 bv = *(bf16x8*)(vb + bytB);
                cc = __builtin_amdgcn_mfma_f32_16x16x32_bf16(as, bv, cc, 0, 0, 0);
            }
            acc[ni2][ei] = cc;
        }
    }
    __syncthreads();

#pragma unroll
    for (int ni2 = 0; ni2 < 2; ++ni2) {
        const int nbase = 16 * (w + 4 * ni2) + 4 * lg;
#pragma unroll
        for (int ei = 0; ei < 4; ++ei) {
            const int e = 16 * ei + lm;
#pragma unroll
            for (int r = 0; r < 4; ++r) {
                int n = nbase + r;
                out[(rowbase + n) * EE + e] = acc[ni2][ei][r] * dinv_lds[n];
            }
        }
    }
}

extern "C" void kernel_launch(void* const* d_in, const int* in_sizes, int n_in,
                              void* d_out, int out_size, void* d_ws, size_t ws_size,
                              hipStream_t stream)
{
    (void)in_sizes; (void)n_in; (void)out_size; (void)ws_size;
    const float* q = (const float*)d_in[0];
    const float* k = (const float*)d_in[1];
    const float* v = (const float*)d_in[2];
    float* out = (float*)d_out;
    unsigned short* kvT = (unsigned short*)d_ws;      // 8 MB bf16 states
    float* ks = (float*)(kvT + KV_ELEMS);             // +256 KB fp32

    la_phase1<<<NBH * NC, 256, 0, stream>>>(k, v, kvT, ks);
    la_phase2<<<288, 64, 0, stream>>>(kvT, ks, out);
    la_phase3<<<NBH * NC, 256, 0, stream>>>(q, k, v, kvT, ks, out);
}